// Round 3
// baseline (817.526 us; speedup 1.0000x reference)
//
#include <hip/hip_runtime.h>
#include <hip/hip_bf16.h>

#define N_NODES 100000
#define N_EDGES 640000
#define NODE_D 128
#define MSG_D 128

typedef __bf16 bf16_t;
typedef __bf16 bf16x8 __attribute__((ext_vector_type(8)));
typedef float f32x4 __attribute__((ext_vector_type(4)));

// ---------------------------------------------------------------------------
// Prep: transpose + convert weights to bf16.
//   WtAB [256][384]: rows 0..127 = W_msg columns, rows 128..255 = W_rev columns
//   WtU  [128][128]: WtU[n][k] = W_upd[k][n]
// ---------------------------------------------------------------------------
__global__ void prep_weights_kernel(const float* __restrict__ Wmsg,
                                    const float* __restrict__ Wrev,
                                    const float* __restrict__ Wupd,
                                    bf16_t* __restrict__ WtAB,
                                    bf16_t* __restrict__ WtU) {
    int idx = blockIdx.x * 256 + threadIdx.x;
    if (idx < 256 * 384) {
        int n = idx / 384;
        int k = idx - n * 384;
        float v = (n < 128) ? Wmsg[k * 128 + n] : Wrev[k * 128 + (n - 128)];
        WtAB[idx] = (bf16_t)v;
    }
    if (idx < 128 * 128) {
        int n = idx / 128;
        int k = idx - n * 128;
        WtU[idx] = (bf16_t)Wupd[k * 128 + n];
    }
}

// ---------------------------------------------------------------------------
// Counting sort of edges by to_idx: hist -> scan -> scatter permutation.
// scatter also materializes permuted from/to index arrays so the edge kernel
// has NO dependent index chain (3 coalesced loads instead of perm->from_idx).
// ---------------------------------------------------------------------------
__global__ void hist_kernel(const int* __restrict__ to_idx, int* __restrict__ hist) {
    int e = blockIdx.x * 256 + threadIdx.x;
    if (e < N_EDGES) atomicAdd(&hist[to_idx[e]], 1);
}

__global__ __launch_bounds__(1024)
void scan_kernel(const int* __restrict__ hist, int* __restrict__ cursor) {
    __shared__ int sums[1024];
    const int T = 1024;
    const int CH = (N_NODES + T - 1) / T;  // 98
    int t = threadIdx.x;
    int lo = t * CH, hi = min(lo + CH, N_NODES);
    int s = 0;
    for (int i = lo; i < hi; ++i) s += hist[i];
    sums[t] = s;
    __syncthreads();
    for (int off = 1; off < T; off <<= 1) {
        int v = (t >= off) ? sums[t - off] : 0;
        __syncthreads();
        sums[t] += v;
        __syncthreads();
    }
    int excl = (t == 0) ? 0 : sums[t - 1];
    for (int i = lo; i < hi; ++i) {
        cursor[i] = excl;
        excl += hist[i];
    }
}

__global__ void scatter_perm_kernel(const int* __restrict__ from_idx,
                                    const int* __restrict__ to_idx,
                                    int* __restrict__ cursor,
                                    int* __restrict__ perm,
                                    int* __restrict__ pfrom,
                                    int* __restrict__ pdst) {
    int e = blockIdx.x * 256 + threadIdx.x;
    if (e < N_EDGES) {
        int t = to_idx[e];
        int pos = atomicAdd(&cursor[t], 1);
        perm[pos] = e;
        pfrom[pos] = from_idx[e];
        pdst[pos] = t;
    }
}

// ---------------------------------------------------------------------------
// Edge kernel (dst-sorted order): per block of 32 permuted edges:
//   gather [node[from]|node[to]|edge_feat] -> bf16 LDS tile A[32][384] (swizzled)
//   GEMM A @ WtAB^T (N=256: msg||rev) via mfma_f32_16x16x32_bf16
//   messages = relu(msg + b_msg) + relu(rev + b_rev)
//   register-merge runs of equal dst, then atomic scatter (dst L2-local)
// BM=32 keeps LDS at ~24.5KB -> 6 blocks/CU (75% occupancy) for latency hiding.
// ---------------------------------------------------------------------------
__global__ __launch_bounds__(256, 6)
void edge_msg_kernel(const float* __restrict__ nodef,
                     const float* __restrict__ edgef,
                     const int* __restrict__ perm,
                     const int* __restrict__ pfrom,
                     const int* __restrict__ pdst,
                     const bf16_t* __restrict__ WtAB,
                     const float* __restrict__ b_msg,
                     const float* __restrict__ b_rev,
                     float* __restrict__ agg) {
    __shared__ char lds_raw[32 * 768];  // A tile: [32 rows][384 cols] bf16, XOR-swizzled
    __shared__ int s_perm[32];
    __shared__ int s_from[32];
    __shared__ int s_dst[32];

    const int tid = threadIdx.x;
    // XCD-chunked swizzle: consecutive dst-ranges stay on one XCD's L2.
    const int wg = (blockIdx.x & 7) * (gridDim.x >> 3) + (blockIdx.x >> 3);
    const int eb = wg * 32;

    if (tid < 32) {
        s_perm[tid] = perm[eb + tid];
        s_from[tid] = pfrom[eb + tid];
        s_dst[tid]  = pdst[eb + tid];
    }
    __syncthreads();

    // ---- stage: 32 rows x 96 float4 = 3072 float4 loads, 12 per thread ----
#pragma unroll
    for (int j = 0; j < 12; ++j) {
        int linear = tid + 256 * j;
        int r = linear / 96;
        int q = linear - r * 96;
        const float* src;
        if (q < 32) {
            src = nodef + (size_t)s_from[r] * 128 + q * 4;
        } else if (q < 64) {
            src = nodef + (size_t)s_dst[r] * 128 + (q - 32) * 4;
        } else {
            src = edgef + (size_t)s_perm[r] * 128 + (q - 64) * 4;
        }
        float4 v = *reinterpret_cast<const float4*>(src);
        union { bf16_t b[4]; uint2 u; } pk;
        pk.b[0] = (bf16_t)v.x; pk.b[1] = (bf16_t)v.y;
        pk.b[2] = (bf16_t)v.z; pk.b[3] = (bf16_t)v.w;
        int byte = (r * 768 + q * 8) ^ ((r & 7) << 4);
        *reinterpret_cast<uint2*>(lds_raw + byte) = pk.u;
    }
    __syncthreads();

    const int wv = tid >> 6;
    const int lane = tid & 63;
    const int lhi = lane >> 4;   // 0..3
    const int llo = lane & 15;   // 0..15

    f32x4 acc[2][4];
#pragma unroll
    for (int m = 0; m < 2; ++m)
#pragma unroll
        for (int n = 0; n < 4; ++n)
            acc[m][n] = (f32x4){0.f, 0.f, 0.f, 0.f};

    // B pointers: n=0,1 -> msg cols wv*32+16n ; n=2,3 -> rev cols (+128)
    const bf16_t* bptr[4];
#pragma unroll
    for (int n = 0; n < 4; ++n) {
        int colb = (n < 2) ? (wv * 32 + 16 * n) : (128 + wv * 32 + 16 * (n - 2));
        bptr[n] = WtAB + (size_t)(colb + llo) * 384 + lhi * 8;
    }

    // ---- K loop: 384 = 12 x 32 ----
#pragma unroll
    for (int k0 = 0; k0 < 12; ++k0) {
        bf16x8 a[2], b[4];
#pragma unroll
        for (int m = 0; m < 2; ++m) {
            int ra = 16 * m + llo;
            int byte = (ra * 768 + (k0 * 32 + lhi * 8) * 2) ^ ((ra & 7) << 4);
            a[m] = *reinterpret_cast<const bf16x8*>(lds_raw + byte);
        }
#pragma unroll
        for (int n = 0; n < 4; ++n)
            b[n] = *reinterpret_cast<const bf16x8*>(bptr[n] + k0 * 32);
#pragma unroll
        for (int m = 0; m < 2; ++m)
#pragma unroll
            for (int n = 0; n < 4; ++n)
                acc[m][n] = __builtin_amdgcn_mfma_f32_16x16x32_bf16(a[m], b[n], acc[m][n], 0, 0, 0);
    }

    // ---- epilogue: relu-sum both nets, merge equal-dst runs, atomic scatter ----
#pragma unroll
    for (int n = 0; n < 2; ++n) {
        int c = wv * 32 + 16 * n + llo;
        float bm = b_msg[c];
        float br = b_rev[c];
        float* aggc = agg + c;
#pragma unroll
        for (int m = 0; m < 2; ++m) {
            int rbase = 16 * m + lhi * 4;
            int pdst0 = s_dst[rbase];
            float pend = fmaxf(acc[m][n][0] + bm, 0.f) + fmaxf(acc[m][n + 2][0] + br, 0.f);
#pragma unroll
            for (int r = 1; r < 4; ++r) {
                int d = s_dst[rbase + r];
                float v = fmaxf(acc[m][n][r] + bm, 0.f) + fmaxf(acc[m][n + 2][r] + br, 0.f);
                if (d == pdst0) {
                    pend += v;
                } else {
                    unsafeAtomicAdd(aggc + (size_t)pdst0 * 128, pend);
                    pdst0 = d;
                    pend = v;
                }
            }
            unsafeAtomicAdd(aggc + (size_t)pdst0 * 128, pend);
        }
    }
}

// ---------------------------------------------------------------------------
// Node update: out = node + relu(agg @ W_upd + b_upd)
// ---------------------------------------------------------------------------
__global__ __launch_bounds__(256, 4)
void node_upd_kernel(const float* __restrict__ agg,
                     const float* __restrict__ nodef,
                     const bf16_t* __restrict__ WtU,
                     const float* __restrict__ b_upd,
                     float* __restrict__ out) {
    __shared__ char lds_raw[64 * 256];  // [64][128] bf16, swizzled

    const int tid = threadIdx.x;
    const int nb = blockIdx.x * 64;

#pragma unroll
    for (int j = 0; j < 8; ++j) {
        int linear = tid + 256 * j;   // 64 rows x 32 float4
        int r = linear / 32;
        int q = linear - r * 32;
        int i = nb + r;
        float4 v = make_float4(0.f, 0.f, 0.f, 0.f);
        if (i < N_NODES)
            v = *reinterpret_cast<const float4*>(agg + (size_t)i * 128 + q * 4);
        union { bf16_t b[4]; uint2 u; } pk;
        pk.b[0] = (bf16_t)v.x; pk.b[1] = (bf16_t)v.y;
        pk.b[2] = (bf16_t)v.z; pk.b[3] = (bf16_t)v.w;
        int byte = (r * 256 + q * 8) ^ ((r & 7) << 4);
        *reinterpret_cast<uint2*>(lds_raw + byte) = pk.u;
    }
    __syncthreads();

    const int wv = tid >> 6;
    const int lane = tid & 63;
    const int lhi = lane >> 4;
    const int llo = lane & 15;

    f32x4 acc[4][2];
#pragma unroll
    for (int m = 0; m < 4; ++m)
#pragma unroll
        for (int n = 0; n < 2; ++n)
            acc[m][n] = (f32x4){0.f, 0.f, 0.f, 0.f};

#pragma unroll
    for (int k0 = 0; k0 < 4; ++k0) {
        bf16x8 a[4], b[2];
#pragma unroll
        for (int m = 0; m < 4; ++m) {
            int ra = 16 * m + llo;
            int byte = (ra * 256 + (k0 * 32 + lhi * 8) * 2) ^ ((ra & 7) << 4);
            a[m] = *reinterpret_cast<const bf16x8*>(lds_raw + byte);
        }
#pragma unroll
        for (int n = 0; n < 2; ++n) {
            int col = wv * 32 + 16 * n + llo;
            b[n] = *reinterpret_cast<const bf16x8*>(WtU + (size_t)col * 128 + k0 * 32 + lhi * 8);
        }
#pragma unroll
        for (int m = 0; m < 4; ++m)
#pragma unroll
            for (int n = 0; n < 2; ++n)
                acc[m][n] = __builtin_amdgcn_mfma_f32_16x16x32_bf16(a[m], b[n], acc[m][n], 0, 0, 0);
    }

#pragma unroll
    for (int m = 0; m < 4; ++m) {
        int rbase = 16 * m + lhi * 4;
#pragma unroll
        for (int r = 0; r < 4; ++r) {
            int i = nb + rbase + r;
            if (i < N_NODES) {
#pragma unroll
                for (int n = 0; n < 2; ++n) {
                    int c = wv * 32 + 16 * n + llo;
                    out[(size_t)i * 128 + c] =
                        nodef[(size_t)i * 128 + c]
                        + fmaxf(acc[m][n][r] + b_upd[c], 0.f);
                }
            }
        }
    }
}

// ---------------------------------------------------------------------------
extern "C" void kernel_launch(void* const* d_in, const int* in_sizes, int n_in,
                              void* d_out, int out_size, void* d_ws, size_t ws_size,
                              hipStream_t stream) {
    const float* nodef    = (const float*)d_in[0];
    const float* edgef    = (const float*)d_in[1];
    const int*   from_idx = (const int*)d_in[2];
    const int*   to_idx   = (const int*)d_in[3];
    const float* Wmsg     = (const float*)d_in[4];
    const float* bmsg     = (const float*)d_in[5];
    const float* Wrev     = (const float*)d_in[6];
    const float* brev     = (const float*)d_in[7];
    const float* Wupd     = (const float*)d_in[8];
    const float* bupd     = (const float*)d_in[9];
    float* out = (float*)d_out;

    char* ws = (char*)d_ws;
    float*  agg    = (float*)ws;                         // 51,200,000 B
    bf16_t* WtAB   = (bf16_t*)(ws + 51200000);           // 196,608 B
    bf16_t* WtU    = (bf16_t*)(ws + 51396608);           // 32,768 B
    int*    hist   = (int*)(ws + 51429376);              // 400,000 B
    int*    cursor = (int*)(ws + 51829376);              // 400,000 B
    int*    perm   = (int*)(ws + 52229376);              // 2,560,000 B
    int*    pfrom  = (int*)(ws + 54789376);              // 2,560,000 B
    int*    pdst   = (int*)(ws + 57349376);              // 2,560,000 B
                                                         // total 59,909,376 B

    hipMemsetAsync(agg, 0, (size_t)N_NODES * MSG_D * sizeof(float), stream);
    hipMemsetAsync(hist, 0, (size_t)N_NODES * sizeof(int), stream);

    prep_weights_kernel<<<384, 256, 0, stream>>>(Wmsg, Wrev, Wupd, WtAB, WtU);
    hist_kernel<<<(N_EDGES + 255) / 256, 256, 0, stream>>>(to_idx, hist);
    scan_kernel<<<1, 1024, 0, stream>>>(hist, cursor);
    scatter_perm_kernel<<<(N_EDGES + 255) / 256, 256, 0, stream>>>(
        from_idx, to_idx, cursor, perm, pfrom, pdst);
    edge_msg_kernel<<<N_EDGES / 32, 256, 0, stream>>>(
        nodef, edgef, perm, pfrom, pdst, WtAB, bmsg, brev, agg);
    node_upd_kernel<<<(N_NODES + 63) / 64, 256, 0, stream>>>(
        agg, nodef, WtU, bupd, out);
}

// Round 4
// 745.493 us; speedup vs baseline: 1.0966x; 1.0966x over previous
//
#include <hip/hip_runtime.h>
#include <hip/hip_bf16.h>

#define N_NODES 100000
#define N_EDGES 640000

typedef __bf16 bf16_t;
typedef __bf16 bf16x8 __attribute__((ext_vector_type(8)));
typedef float f32x4 __attribute__((ext_vector_type(4)));

// ---------------------------------------------------------------------------
// Prep: transpose + convert weights to bf16.
//   WtAB [256][384]: rows 0..127 = W_msg columns, rows 128..255 = W_rev columns
//   WtU  [128][128]: WtU[n][p] = W_upd[pi(p)][n], where pi is the stored-column
//   permutation of the msgs array: pi(p) = 32*(p>>5) + ((p>>1)&15) + 16*(p&1)
//   (phase A packs lane columns (c, c+16) into one u32 pair).
// ---------------------------------------------------------------------------
__global__ void prep_weights_kernel(const float* __restrict__ Wmsg,
                                    const float* __restrict__ Wrev,
                                    const float* __restrict__ Wupd,
                                    bf16_t* __restrict__ WtAB,
                                    bf16_t* __restrict__ WtU) {
    int idx = blockIdx.x * 256 + threadIdx.x;
    if (idx < 256 * 384) {
        int n = idx / 384;
        int k = idx - n * 384;
        float v = (n < 128) ? Wmsg[k * 128 + n] : Wrev[k * 128 + (n - 128)];
        WtAB[idx] = (bf16_t)v;
    }
    if (idx < 128 * 128) {
        int n = idx >> 7;
        int p = idx & 127;
        int colp = 32 * (p >> 5) + ((p >> 1) & 15) + 16 * (p & 1);
        WtU[idx] = (bf16_t)Wupd[colp * 128 + n];
    }
}

// ---------------------------------------------------------------------------
// CSR build: hist -> scan (row_start + cursor) -> inverse permutation.
// ---------------------------------------------------------------------------
__global__ void hist_kernel(const int* __restrict__ to_idx, int* __restrict__ hist) {
    int e = blockIdx.x * 256 + threadIdx.x;
    if (e < N_EDGES) atomicAdd(&hist[to_idx[e]], 1);
}

__global__ __launch_bounds__(1024)
void scan_kernel(const int* __restrict__ hist,
                 int* __restrict__ cursor,
                 int* __restrict__ row_start) {
    __shared__ int sums[1024];
    const int T = 1024;
    const int CH = (N_NODES + T - 1) / T;  // 98
    int t = threadIdx.x;
    int lo = t * CH, hi = min(lo + CH, N_NODES);
    int s = 0;
    for (int i = lo; i < hi; ++i) s += hist[i];
    sums[t] = s;
    __syncthreads();
    for (int off = 1; off < T; off <<= 1) {
        int v = (t >= off) ? sums[t - off] : 0;
        __syncthreads();
        sums[t] += v;
        __syncthreads();
    }
    int excl = (t == 0) ? 0 : sums[t - 1];
    for (int i = lo; i < hi; ++i) {
        cursor[i] = excl;
        row_start[i] = excl;
        excl += hist[i];
    }
    if (t == T - 1) row_start[N_NODES] = excl;  // = N_EDGES
}

__global__ void inv_scatter_kernel(const int* __restrict__ to_idx,
                                   int* __restrict__ cursor,
                                   int* __restrict__ inv) {
    int e = blockIdx.x * 256 + threadIdx.x;
    if (e < N_EDGES) {
        int pos = atomicAdd(&cursor[to_idx[e]], 1);
        inv[e] = pos;
    }
}

// ---------------------------------------------------------------------------
// Phase A: edge GEMM in ORIGINAL edge order (all streaming except L3-resident
// nodef gathers). Per block of 64 edges:
//   gather [node[from]|node[to]|edge_feat] -> bf16 LDS tile A[64][384] (swizzled)
//   GEMM A @ WtAB^T (N=256: msg||rev), relu-sum the two nets,
//   STORE packed-bf16 message row at dst-sorted position inv[e]. No atomics.
// ---------------------------------------------------------------------------
__global__ __launch_bounds__(256, 3)
void edge_msg_kernel(const float* __restrict__ nodef,
                     const float* __restrict__ edgef,
                     const int* __restrict__ from_idx,
                     const int* __restrict__ to_idx,
                     const int* __restrict__ inv,
                     const bf16_t* __restrict__ WtAB,
                     const float* __restrict__ b_msg,
                     const float* __restrict__ b_rev,
                     unsigned int* __restrict__ msgs_u) {
    __shared__ char lds_raw[64 * 768];  // A tile: [64 rows][384 cols] bf16, XOR-swizzled
    __shared__ int s_from[64], s_dst[64], s_inv[64];

    const int tid = threadIdx.x;
    const int eb = blockIdx.x * 64;

    if (tid < 64) {
        s_from[tid] = from_idx[eb + tid];
        s_dst[tid]  = to_idx[eb + tid];
        s_inv[tid]  = inv[eb + tid];
    }
    __syncthreads();

    // ---- stage: 64 rows x 96 float4 = 6144 float4 loads, 24 per thread ----
#pragma unroll
    for (int j = 0; j < 24; ++j) {
        int linear = tid + 256 * j;
        int r = linear / 96;
        int q = linear - r * 96;
        const float* src;
        if (q < 32) {
            src = nodef + (size_t)s_from[r] * 128 + q * 4;
        } else if (q < 64) {
            src = nodef + (size_t)s_dst[r] * 128 + (q - 32) * 4;
        } else {
            src = edgef + (size_t)(eb + r) * 128 + (q - 64) * 4;
        }
        float4 v = *reinterpret_cast<const float4*>(src);
        union { bf16_t b[4]; uint2 u; } pk;
        pk.b[0] = (bf16_t)v.x; pk.b[1] = (bf16_t)v.y;
        pk.b[2] = (bf16_t)v.z; pk.b[3] = (bf16_t)v.w;
        int byte = (r * 768 + q * 8) ^ ((r & 7) << 4);
        *reinterpret_cast<uint2*>(lds_raw + byte) = pk.u;
    }
    __syncthreads();

    const int wv = tid >> 6;
    const int lane = tid & 63;
    const int lhi = lane >> 4;   // 0..3
    const int llo = lane & 15;   // 0..15

    f32x4 acc[4][4];
#pragma unroll
    for (int m = 0; m < 4; ++m)
#pragma unroll
        for (int n = 0; n < 4; ++n)
            acc[m][n] = (f32x4){0.f, 0.f, 0.f, 0.f};

    // B pointers: n=0,1 -> msg cols wv*32+16n ; n=2,3 -> rev cols (+128)
    const bf16_t* bptr[4];
#pragma unroll
    for (int n = 0; n < 4; ++n) {
        int colb = (n < 2) ? (wv * 32 + 16 * n) : (128 + wv * 32 + 16 * (n - 2));
        bptr[n] = WtAB + (size_t)(colb + llo) * 384 + lhi * 8;
    }

    // ---- K loop: 384 = 12 x 32 ----
#pragma unroll
    for (int k0 = 0; k0 < 12; ++k0) {
        bf16x8 a[4], b[4];
#pragma unroll
        for (int m = 0; m < 4; ++m) {
            int ra = 16 * m + llo;
            int byte = (ra * 768 + (k0 * 32 + lhi * 8) * 2) ^ ((ra & 7) << 4);
            a[m] = *reinterpret_cast<const bf16x8*>(lds_raw + byte);
        }
#pragma unroll
        for (int n = 0; n < 4; ++n)
            b[n] = *reinterpret_cast<const bf16x8*>(bptr[n] + k0 * 32);
#pragma unroll
        for (int m = 0; m < 4; ++m)
#pragma unroll
            for (int n = 0; n < 4; ++n)
                acc[m][n] = __builtin_amdgcn_mfma_f32_16x16x32_bf16(a[m], b[n], acc[m][n], 0, 0, 0);
    }

    // ---- epilogue: relu-sum both nets, pack bf16 pair, store at inv row ----
    const int c0 = wv * 32 + llo;
    const float bm0 = b_msg[c0], br0 = b_rev[c0];
    const float bm1 = b_msg[c0 + 16], br1 = b_rev[c0 + 16];
#pragma unroll
    for (int m = 0; m < 4; ++m) {
        int rbase = 16 * m + lhi * 4;
#pragma unroll
        for (int r = 0; r < 4; ++r) {
            float v0 = fmaxf(acc[m][0][r] + bm0, 0.f) + fmaxf(acc[m][2][r] + br0, 0.f);
            float v1 = fmaxf(acc[m][1][r] + bm1, 0.f) + fmaxf(acc[m][3][r] + br1, 0.f);
            union { bf16_t b[2]; unsigned int u; } pk;
            pk.b[0] = (bf16_t)v0;
            pk.b[1] = (bf16_t)v1;
            msgs_u[(size_t)s_inv[rbase + r] * 64 + wv * 16 + llo] = pk.u;
        }
    }
}

// ---------------------------------------------------------------------------
// Phase B: per block of 64 nodes:
//   f32 register segsum of each node's CONTIGUOUS msgs range (CSR),
//   -> bf16 LDS tile [64][128] (swizzled, stored-column order),
//   MFMA with pi-baked WtU, residual + relu, store out.
// ---------------------------------------------------------------------------
__global__ __launch_bounds__(256, 4)
void node_upd_kernel(const unsigned int* __restrict__ msgs_u,
                     const int* __restrict__ row_start,
                     const float* __restrict__ nodef,
                     const bf16_t* __restrict__ WtU,
                     const float* __restrict__ b_upd,
                     float* __restrict__ out) {
    __shared__ char lds_raw[64 * 256];  // [64][128] bf16, swizzled
    __shared__ int s_rs[65];

    const int tid = threadIdx.x;
    const int nb = blockIdx.x * 64;

    if (tid < 65) {
        int nid = nb + tid;
        s_rs[tid] = (nid <= N_NODES) ? row_start[nid] : N_EDGES;
    }
    __syncthreads();

    {
        const int r = tid >> 2;      // node row 0..63
        const int q = tid & 3;       // 32-column chunk
        float s[32];
#pragma unroll
        for (int i = 0; i < 32; ++i) s[i] = 0.f;
        const int rs = s_rs[r], re = s_rs[r + 1];
        for (int e = rs; e < re; ++e) {
            const uint4* p = reinterpret_cast<const uint4*>(msgs_u + (size_t)e * 64 + q * 16);
#pragma unroll
            for (int i = 0; i < 4; ++i) {
                uint4 w = p[i];
                s[8*i+0] += __uint_as_float(w.x << 16);
                s[8*i+1] += __uint_as_float(w.x & 0xffff0000u);
                s[8*i+2] += __uint_as_float(w.y << 16);
                s[8*i+3] += __uint_as_float(w.y & 0xffff0000u);
                s[8*i+4] += __uint_as_float(w.z << 16);
                s[8*i+5] += __uint_as_float(w.z & 0xffff0000u);
                s[8*i+6] += __uint_as_float(w.w << 16);
                s[8*i+7] += __uint_as_float(w.w & 0xffff0000u);
            }
        }
        // bf16-pack into LDS (swizzled), stored-column order
#pragma unroll
        for (int i = 0; i < 4; ++i) {
            union { bf16_t b[8]; uint4 u; } pk;
#pragma unroll
            for (int w = 0; w < 8; ++w) pk.b[w] = (bf16_t)s[8*i + w];
            int byte = (r * 256 + q * 64 + i * 16) ^ ((r & 7) << 4);
            *reinterpret_cast<uint4*>(lds_raw + byte) = pk.u;
        }
    }
    __syncthreads();

    const int wv = tid >> 6;
    const int lane = tid & 63;
    const int lhi = lane >> 4;
    const int llo = lane & 15;

    f32x4 acc[4][2];
#pragma unroll
    for (int m = 0; m < 4; ++m)
#pragma unroll
        for (int n = 0; n < 2; ++n)
            acc[m][n] = (f32x4){0.f, 0.f, 0.f, 0.f};

#pragma unroll
    for (int k0 = 0; k0 < 4; ++k0) {
        bf16x8 a[4], b[2];
#pragma unroll
        for (int m = 0; m < 4; ++m) {
            int ra = 16 * m + llo;
            int byte = (ra * 256 + (k0 * 32 + lhi * 8) * 2) ^ ((ra & 7) << 4);
            a[m] = *reinterpret_cast<const bf16x8*>(lds_raw + byte);
        }
#pragma unroll
        for (int n = 0; n < 2; ++n) {
            int col = wv * 32 + 16 * n + llo;
            b[n] = *reinterpret_cast<const bf16x8*>(WtU + (size_t)col * 128 + k0 * 32 + lhi * 8);
        }
#pragma unroll
        for (int m = 0; m < 4; ++m)
#pragma unroll
            for (int n = 0; n < 2; ++n)
                acc[m][n] = __builtin_amdgcn_mfma_f32_16x16x32_bf16(a[m], b[n], acc[m][n], 0, 0, 0);
    }

#pragma unroll
    for (int m = 0; m < 4; ++m) {
        int rbase = 16 * m + lhi * 4;
#pragma unroll
        for (int r = 0; r < 4; ++r) {
            int i = nb + rbase + r;
            if (i < N_NODES) {
#pragma unroll
                for (int n = 0; n < 2; ++n) {
                    int c = wv * 32 + 16 * n + llo;
                    out[(size_t)i * 128 + c] =
                        nodef[(size_t)i * 128 + c]
                        + fmaxf(acc[m][n][r] + b_upd[c], 0.f);
                }
            }
        }
    }
}

// ---------------------------------------------------------------------------
extern "C" void kernel_launch(void* const* d_in, const int* in_sizes, int n_in,
                              void* d_out, int out_size, void* d_ws, size_t ws_size,
                              hipStream_t stream) {
    const float* nodef    = (const float*)d_in[0];
    const float* edgef    = (const float*)d_in[1];
    const int*   from_idx = (const int*)d_in[2];
    const int*   to_idx   = (const int*)d_in[3];
    const float* Wmsg     = (const float*)d_in[4];
    const float* bmsg     = (const float*)d_in[5];
    const float* Wrev     = (const float*)d_in[6];
    const float* brev     = (const float*)d_in[7];
    const float* Wupd     = (const float*)d_in[8];
    const float* bupd     = (const float*)d_in[9];
    float* out = (float*)d_out;

    char* ws = (char*)d_ws;
    unsigned int* msgs_u   = (unsigned int*)ws;             // 163,840,000 B
    bf16_t*       WtAB     = (bf16_t*)(ws + 163840000);     // 196,608 B
    bf16_t*       WtU      = (bf16_t*)(ws + 164036608);     // 32,768 B
    int*          hist     = (int*)(ws + 164069376);        // 400,000 B
    int*          cursor   = (int*)(ws + 164469376);        // 400,000 B
    int*          rowstart = (int*)(ws + 164869376);        // 400,004 B (padded)
    int*          inv      = (int*)(ws + 165269392);        // 2,560,000 B
                                                            // total 167,829,392 B

    hipMemsetAsync(hist, 0, (size_t)N_NODES * sizeof(int), stream);

    prep_weights_kernel<<<384, 256, 0, stream>>>(Wmsg, Wrev, Wupd, WtAB, WtU);
    hist_kernel<<<(N_EDGES + 255) / 256, 256, 0, stream>>>(to_idx, hist);
    scan_kernel<<<1, 1024, 0, stream>>>(hist, cursor, rowstart);
    inv_scatter_kernel<<<(N_EDGES + 255) / 256, 256, 0, stream>>>(to_idx, cursor, inv);
    edge_msg_kernel<<<N_EDGES / 64, 256, 0, stream>>>(
        nodef, edgef, from_idx, to_idx, inv, WtAB, bmsg, brev, msgs_u);
    node_upd_kernel<<<(N_NODES + 63) / 64, 256, 0, stream>>>(
        msgs_u, rowstart, nodef, WtU, bupd, out);
}